// Round 10
// baseline (194.800 us; speedup 1.0000x reference)
//
#include <hip/hip_runtime.h>
#include <math.h>

#define BB 32
#define SS 1025
#define DD 64
#define HH 8
#define IN_D 8
#define NPATCH 1024
#define OUTD 9
#define EPSF 1e-5f
#define SD (SS*DD)        // 65600
#define SP 1056           // padded seq = 33*32
#define NQT 65            // ceil(1025/16) q-tiles
#define NCH 33            // 1056/32 t-chunks
#define VTROW 1064        // VT LDS row stride (shorts)
#define PSTR 40           // P row stride in shorts ([q][t], 32 t + 8 pad); 80B keeps b128 reads aligned
#define NTB 257           // blocks per batch for token/stat kernels
#define ZROW 1055         // guaranteed-zero K row (pad, zeroed by k_qkv)

typedef __attribute__((ext_vector_type(8))) short bf16x8;
typedef __attribute__((ext_vector_type(4))) float f32x4;

// fold softmax scale 1/sqrt(8) and exp->exp2 into Q
#define SCALE_LOG2E (0.35355339059327378f * 1.4426950408889634f)

#if __has_builtin(__builtin_amdgcn_exp2f)
__device__ __forceinline__ float exp2_fast(float x) { return __builtin_amdgcn_exp2f(x); }
#else
__device__ __forceinline__ float exp2_fast(float x) {
    float r; asm("v_exp_f32 %0, %1" : "=v"(r) : "v"(x)); return r;
}
#endif

__device__ __forceinline__ short f2bf(float f) {
    union { float f; unsigned u; } a; a.f = f;
    unsigned r = a.u + 0x7FFFu + ((a.u >> 16) & 1u);  // RNE
    return (short)(r >> 16);
}
__device__ __forceinline__ short f2bf_fast(float f) {   // round-to-nearest, ties away
    return (short)((__float_as_uint(f) + 0x8000u) >> 16);
}

// ---------------- tokens = [cls; patches@w_map+b_map] + pos; per-block partial ln1 stats ----------------
__global__ void k_tokens(const float* __restrict__ images, const float* __restrict__ w_map,
                         const float* __restrict__ b_map, const float* __restrict__ cls,
                         float* __restrict__ tokens, float* __restrict__ part1,
                         float* __restrict__ partq1, float* __restrict__ sum2,
                         float* __restrict__ sumsq2) {
    int b = blockIdx.y;
    int bx = blockIdx.x;
    int idx = bx * 256 + threadIdx.x;   // [0, SD)
    int tid = threadIdx.x;
    __shared__ float recip[64];
    __shared__ float sh[512];
    if (tid < 64) {
        int j = tid;
        float div;
        if ((j & 1) == 0)
            div = powf(10000.0f, (float)j * (1.0f / 64.0f));
        else  // reference: 10000^(j-1)/64; overflow->inf -> recip 0 -> arg 0 -> cos=1 (matches f64)
            div = powf(10000.0f, (float)(j - 1)) * (1.0f / 64.0f);
        recip[j] = 1.0f / div;
    }
    __syncthreads();
    float lv = 0.f, lvv = 0.f;
    if (idx < SD) {
        int s = idx >> 6, j = idx & 63;
        float arg = (float)s * recip[j];
        float pv = (j & 1) ? __cosf(arg) : __sinf(arg);
        float v;
        if (s == 0) {
            v = cls[j];
        } else {
            const float* p = images + (size_t)b * (NPATCH * IN_D) + (size_t)(s - 1) * IN_D;
            float acc = b_map[j];
#pragma unroll
            for (int i = 0; i < IN_D; ++i) acc += p[i] * w_map[i * DD + j];
            v = acc;
        }
        v += pv;
        tokens[(size_t)b * SD + idx] = v;
        lv = v; lvv = v * v;
    }
    sh[tid] = lv; sh[256 + tid] = lvv;
    __syncthreads();
    for (int off = 128; off > 0; off >>= 1) {
        if (tid < off) { sh[tid] += sh[tid + off]; sh[256 + tid] += sh[256 + tid + off]; }
        __syncthreads();
    }
    if (tid == 0) {
        part1[b * NTB + bx] = sh[0];
        partq1[b * NTB + bx] = sh[256];
    }
    if (bx == 0) {          // zero the ln2 stat accumulators (k_attn adds later; stream-ordered)
        if (tid == 0) sum2[b] = 0.f;
        if (tid == 1) sumsq2[b] = 0.f;
    }
}

// ---------------- ln1 -> q,k,v in bf16, layout [bh][SP][8]; scale*log2e folded into q ----------------
// Last block per batch additionally zeroes kb pad rows [SS, SP) — required because
// k_attn reads K directly from global (garbage pad -> exp -> inf*0 = NaN would poison PV).
__global__ void k_qkv(const float* __restrict__ tokens, const float* __restrict__ part1,
                      const float* __restrict__ partq1, const float* __restrict__ g1,
                      const float* __restrict__ be1,
                      const float* __restrict__ wq, const float* __restrict__ bq,
                      const float* __restrict__ wk, const float* __restrict__ bk,
                      const float* __restrict__ wv, const float* __restrict__ bv,
                      short* __restrict__ qb, short* __restrict__ kb, short* __restrict__ vb) {
    int b = blockIdx.y, bx = blockIdx.x, tid = threadIdx.x;
    __shared__ float sh[512];
    __shared__ float xs[4][DD];
    __shared__ float stats[2];
    {
        float s = 0.f, ss = 0.f;
        for (int i = tid; i < NTB; i += 256) { s += part1[b * NTB + i]; ss += partq1[b * NTB + i]; }
        sh[tid] = s; sh[256 + tid] = ss;
        __syncthreads();
        for (int off = 128; off > 0; off >>= 1) {
            if (tid < off) { sh[tid] += sh[tid + off]; sh[256 + tid] += sh[256 + tid + off]; }
            __syncthreads();
        }
        if (tid == 0) {
            float mu = sh[0] / (float)SD;
            float var = sh[256] / (float)SD - mu * mu;
            stats[0] = mu;
            stats[1] = rsqrtf(var + EPSF);
        }
        __syncthreads();
    }
    int r = tid >> 6, d = tid & 63;
    int srow = bx * 4 + r;
    if (srow < SS) {
        float t = tokens[((size_t)b * SS + srow) * DD + d];
        xs[r][d] = (t - stats[0]) * stats[1] * g1[srow * DD + d] + be1[srow * DD + d];
    }
    __syncthreads();
    for (int o = tid; o < 768; o += 256) {
        int rr = o / 192;
        int rem = o % 192;
        int which = rem / 64;       // 0=q 1=k 2=v
        int he = rem % 64;
        int h = he >> 3, e = he & 7;
        int s2 = bx * 4 + rr;
        if (s2 >= SS) continue;
        const float* w = (which == 0) ? wq : (which == 1) ? wk : wv;
        const float* bias = (which == 0) ? bq : (which == 1) ? bk : bv;
        float acc = bias[he];
#pragma unroll
        for (int dd = 0; dd < 8; ++dd)
            acc += xs[rr][h * 8 + dd] * w[(h * 8 + dd) * 8 + e];
        if (which == 0) acc *= SCALE_LOG2E;
        short* dst = (which == 0) ? qb : (which == 1) ? kb : vb;
        dst[((size_t)(b * HH + h) * SP + s2) * 8 + e] = f2bf(acc);
    }
    if (bx == NTB - 1) {
        // zero K pad rows [SS, SP) for all heads of this batch: (SP-SS)*HH*8 = 15872 shorts
        for (int i = tid; i < (SP - SS) * HH * 8; i += 256) {
            int rr = i / (HH * 8);          // pad row index 0..30
            int he = i % (HH * 8);
            int hh = he >> 3, e = he & 7;
            kb[((size_t)(b * HH + hh) * SP + SS + rr) * 8 + e] = 0;
        }
    }
}

// ---------------- MFMA flash attention; CLS-row output + ln2-stat accumulation ----------------
// grid (4, HH, BB), 512 thr (8 waves); 1024 blocks = 4/CU (LDS 39632 B, VGPR<=64).
// K read directly from global (L2) with 1-deep register prefetch (alias-free).
// P path: TRUE double-buffered pipeline — read P(ch)/V(ch) from parity buffer ch&1,
// then compute+write S(ch+1) into parity (ch+1)&1 (DISJOINT lines: no WAR hazard —
// this is the safe version of R4's failed single-buffer overlap), then PV-MFMA consumes.
// Same-address write(iter n-1)->read(iter n) ordering is the R3/R5-proven DS guarantee.
__global__ __launch_bounds__(512, 8)
void k_attn(const short* __restrict__ qb, const short* __restrict__ kb, const short* __restrict__ vb,
            const float* __restrict__ tokens, float* __restrict__ out0,
            float* __restrict__ sum2, float* __restrict__ sumsq2) {
    __shared__ __align__(16) short VTs[9 * VTROW];       // 19152 B: V^T rows [e][t]; row 8 = ones(t<SS)
    __shared__ __align__(16) short Ps[8 * 2 * 16 * PSTR];// 20480 B: per-wave double-buffered P [q][t]
    int h = blockIdx.y, b = blockIdx.z;
    int bh = b * HH + h;
    int tid = threadIdx.x;
    int wave = tid >> 6, lane = tid & 63;
    int col = lane & 15, quad = lane >> 4;

    bf16x8 z8 = {0, 0, 0, 0, 0, 0, 0, 0};
    {   // transpose V into VT; row 8 = softmax-denominator ones row (0 in pad: excludes pad P=1 terms)
        const bf16x8* vg = (const bf16x8*)(vb + (size_t)bh * SP * 8);
        for (int t = tid; t < SP; t += 512) {
            if (t < SS) {
                bf16x8 row = vg[t];
#pragma unroll
                for (int e = 0; e < 8; ++e) VTs[e * VTROW + t] = row[e];
                VTs[8 * VTROW + t] = (short)0x3F80;   // bf16 1.0
            } else {
#pragma unroll
                for (int e = 0; e < 9; ++e) VTs[e * VTROW + t] = 0;
            }
        }
    }
    __syncthreads();

    // K B-frag straight from global: quad0 lanes walk rows t0+col / t0+col+16;
    // quads 1-3 read the zeroed pad row (same address across lanes -> broadcast).
    const short* kg = kb + (size_t)bh * SP * 8;
    const short* kp0 = kg + ((quad == 0) ? col * 8 : ZROW * 8);
    const int kstep = (quad == 0) ? 256 : 0;     // shorts per 32-t chunk
    const int koff16 = (quad == 0) ? 128 : 0;
    // V B-frag: lane n=col -> VT row e; cols 9-15 read the ones row (their O columns
    // are computed but never read in the epilogue — harmless finite values)
    const short* vbase_l = VTs + (col < 9 ? col : 8) * VTROW + quad * 8;
    short* pbase = Ps + wave * (2 * 16 * PSTR);
    short* pwr = pbase + (quad * 4) * PSTR + col;        // S-write base (+parity, +r*PSTR)
    const short* prd = pbase + col * PSTR + quad * 8;    // P-read base (+parity)

    float lsum = 0.f, lssq = 0.f;
    int slot = blockIdx.x * 8 + wave;   // 0..31

    for (int qt = slot; qt < NQT; qt += 32) {
        bf16x8 qfrag = z8;
        if (quad == 0) qfrag = *(const bf16x8*)(qb + ((size_t)bh * SP + qt * 16 + col) * 8);
        f32x4 o = {0.f, 0.f, 0.f, 0.f};
        const f32x4 zz = {0.f, 0.f, 0.f, 0.f};
        const short* kptr = kp0;
        // K register prefetch for chunk 0, and emit S(0) into parity buffer 0
        bf16x8 ka = *(const bf16x8*)kptr;
        bf16x8 kb_ = *(const bf16x8*)(kptr + koff16);
        {
            f32x4 s0 = __builtin_amdgcn_mfma_f32_16x16x32_bf16(qfrag, ka, zz, 0, 0, 0);
            f32x4 s1 = __builtin_amdgcn_mfma_f32_16x16x32_bf16(qfrag, kb_, zz, 0, 0, 0);
#pragma unroll
            for (int r = 0; r < 4; ++r) {
                pwr[r * PSTR]      = f2bf_fast(exp2_fast(s0[r]));
                pwr[r * PSTR + 16] = f2bf_fast(exp2_fast(s1[r]));
            }
        }
        for (int ch = 0; ch < NCH; ++ch) {
            // issue P(ch) + V(ch) reads from parity ch&1 (latency overlaps S(ch+1) below)
            bf16x8 pf = *(const bf16x8*)(prd + (ch & 1) * (16 * PSTR));
            bf16x8 vf = *(const bf16x8*)(vbase_l + ch * 32);
            if (ch + 1 < NCH) {
                // prefetch K(ch+1) (registers — alias-free) and emit S(ch+1) into parity (ch+1)&1
                kptr += kstep;
                ka = *(const bf16x8*)kptr;
                kb_ = *(const bf16x8*)(kptr + koff16);
                f32x4 s0 = __builtin_amdgcn_mfma_f32_16x16x32_bf16(qfrag, ka, zz, 0, 0, 0);
                f32x4 s1 = __builtin_amdgcn_mfma_f32_16x16x32_bf16(qfrag, kb_, zz, 0, 0, 0);
                short* pw = pwr + ((ch + 1) & 1) * (16 * PSTR);
#pragma unroll
                for (int r = 0; r < 4; ++r) {
                    pw[r * PSTR]      = f2bf_fast(exp2_fast(s0[r]));
                    pw[r * PSTR + 16] = f2bf_fast(exp2_fast(s1[r]));
                }
            }
            o = __builtin_amdgcn_mfma_f32_16x16x32_bf16(pf, vf, o, 0, 0, 0);
        }
        // epilogue: spill O via per-wave scratch (col 8 = softmax denom l)
        float* Pf = (float*)pbase;
#pragma unroll
        for (int r = 0; r < 4; ++r) Pf[(quad * 4 + r) * 16 + col] = o[r];
#pragma unroll
        for (int pass = 0; pass < 2; ++pass) {
            int idx = lane + pass * 64;    // 16q x 8e
            int qq = idx >> 3, e = idx & 7;
            int qg = qt * 16 + qq;
            if (qg < SS) {
                float num = Pf[qq * 16 + e];
                float l = Pf[qq * 16 + 8];
                float ov = tokens[((size_t)b * SS + qg) * DD + h * 8 + e] + num / l;
                lsum += ov; lssq += ov * ov;
                if (qg == 0) out0[b * DD + h * 8 + e] = ov;
            }
        }
    }

    __syncthreads();
    float* red = (float*)Ps;    // P scratch dead; reuse (needs 4 KB of 20 KB)
    red[tid] = lsum; red[512 + tid] = lssq;
    __syncthreads();
    for (int off = 256; off > 0; off >>= 1) {
        if (tid < off) { red[tid] += red[tid + off]; red[512 + tid] += red[512 + tid + off]; }
        __syncthreads();
    }
    if (tid == 0) {
        atomicAdd(&sum2[b], red[0]);
        atomicAdd(&sumsq2[b], red[512]);
    }
}

// ---------------- final: ln2(row0) -> MLP(+relu) -> residual -> head -> softmax ----------------
__global__ void k_final(const float* __restrict__ out0, const float* __restrict__ sum2,
                        const float* __restrict__ sumsq2, const float* __restrict__ g2,
                        const float* __restrict__ be2, const float* __restrict__ w_enc,
                        const float* __restrict__ b_enc, const float* __restrict__ w_out,
                        const float* __restrict__ b_out, float* __restrict__ out) {
    int b = blockIdx.x;
    int tid = threadIdx.x;  // 64
    __shared__ float xn[DD], hsh[DD], logit[OUTD];
    float n = (float)SD;
    float mu = sum2[b] / n;
    float var = sumsq2[b] / n - mu * mu;
    float rs = rsqrtf(var + EPSF);
    float o = out0[b * DD + tid];
    xn[tid] = (o - mu) * rs * g2[tid] + be2[tid];
    __syncthreads();
    float acc = b_enc[tid];
#pragma unroll
    for (int d = 0; d < DD; ++d) acc += xn[d] * w_enc[d * DD + tid];
    hsh[tid] = o + fmaxf(acc, 0.f);
    __syncthreads();
    if (tid < OUTD) {
        float a = b_out[tid];
#pragma unroll
        for (int d = 0; d < DD; ++d) a += hsh[d] * w_out[d * OUTD + tid];
        logit[tid] = a;
    }
    __syncthreads();
    if (tid == 0) {
        float m = logit[0];
        for (int i = 1; i < OUTD; ++i) m = fmaxf(m, logit[i]);
        float p[OUTD]; float ssum = 0.f;
        for (int i = 0; i < OUTD; ++i) { p[i] = expf(logit[i] - m); ssum += p[i]; }
        for (int i = 0; i < OUTD; ++i) out[b * OUTD + i] = p[i] / ssum;
    }
}

extern "C" void kernel_launch(void* const* d_in, const int* in_sizes, int n_in,
                              void* d_out, int out_size, void* d_ws, size_t ws_size,
                              hipStream_t stream) {
    const float* images = (const float*)d_in[0];
    const float* w_map  = (const float*)d_in[1];
    const float* b_map  = (const float*)d_in[2];
    const float* cls    = (const float*)d_in[3];
    const float* g1     = (const float*)d_in[4];
    const float* be1    = (const float*)d_in[5];
    const float* wq     = (const float*)d_in[6];
    const float* bq     = (const float*)d_in[7];
    const float* wk     = (const float*)d_in[8];
    const float* bk     = (const float*)d_in[9];
    const float* wv     = (const float*)d_in[10];
    const float* bv     = (const float*)d_in[11];
    const float* g2     = (const float*)d_in[12];
    const float* be2    = (const float*)d_in[13];
    const float* w_enc  = (const float*)d_in[14];
    const float* b_enc  = (const float*)d_in[15];
    const float* w_out  = (const float*)d_in[16];
    const float* b_out  = (const float*)d_in[17];
    float* out = (float*)d_out;

    float* ws = (float*)d_ws;
    size_t off = 0;
    float* tokens = ws + off; off += (size_t)BB * SD;
    float* out0   = ws + off; off += BB * DD;
    float* part1  = ws + off; off += BB * NTB;
    float* partq1 = ws + off; off += BB * NTB;
    float* sum2   = ws + off; off += BB;
    float* sumsq2 = ws + off; off += BB;
    short* qb = (short*)(ws + off); off += (size_t)BB * HH * SP * 8 / 2;
    short* kb = (short*)(ws + off); off += (size_t)BB * HH * SP * 8 / 2;
    short* vb = (short*)(ws + off); off += (size_t)BB * HH * SP * 8 / 2;

    k_tokens<<<dim3(NTB, BB), 256, 0, stream>>>(images, w_map, b_map, cls, tokens,
                                                part1, partq1, sum2, sumsq2);
    k_qkv<<<dim3(NTB, BB), 256, 0, stream>>>(tokens, part1, partq1, g1, be1,
                                             wq, bq, wk, bk, wv, bv, qb, kb, vb);
    k_attn<<<dim3(4, HH, BB), 512, 0, stream>>>(qb, kb, vb, tokens, out0, sum2, sumsq2);
    k_final<<<BB, DD, 0, stream>>>(out0, sum2, sumsq2, g2, be2, w_enc, b_enc, w_out, b_out, out);
}

// Round 11
// 186.915 us; speedup vs baseline: 1.0422x; 1.0422x over previous
//
#include <hip/hip_runtime.h>
#include <math.h>

#define BB 32
#define SS 1025
#define DD 64
#define HH 8
#define IN_D 8
#define NPATCH 1024
#define OUTD 9
#define EPSF 1e-5f
#define SD (SS*DD)        // 65600
#define SP 1056           // padded seq = 33*32
#define NQT 65            // ceil(1025/16) q-tiles
#define NCH 33            // 1056/32 t-chunks
#define VTROW 1064        // VT LDS row stride (shorts)
#define PSTR 40           // P row stride in shorts ([q][t], 32 t + 8 pad); 80B keeps b128 reads aligned
#define NTB 257           // blocks per batch for token/stat kernels
#define ZROW 1055         // guaranteed-zero K row (pad, zeroed by k_qkv)

typedef __attribute__((ext_vector_type(8))) short bf16x8;
typedef __attribute__((ext_vector_type(4))) float f32x4;

// fold softmax scale 1/sqrt(8) and exp->exp2 into Q
#define SCALE_LOG2E (0.35355339059327378f * 1.4426950408889634f)

#if __has_builtin(__builtin_amdgcn_exp2f)
__device__ __forceinline__ float exp2_fast(float x) { return __builtin_amdgcn_exp2f(x); }
#else
__device__ __forceinline__ float exp2_fast(float x) {
    float r; asm("v_exp_f32 %0, %1" : "=v"(r) : "v"(x)); return r;
}
#endif

__device__ __forceinline__ short f2bf(float f) {
    union { float f; unsigned u; } a; a.f = f;
    unsigned r = a.u + 0x7FFFu + ((a.u >> 16) & 1u);  // RNE
    return (short)(r >> 16);
}
__device__ __forceinline__ short f2bf_fast(float f) {   // round-to-nearest, ties away
    return (short)((__float_as_uint(f) + 0x8000u) >> 16);
}

// ---------------- tokens = [cls; patches@w_map+b_map] + pos; per-block partial ln1 stats ----------------
__global__ void k_tokens(const float* __restrict__ images, const float* __restrict__ w_map,
                         const float* __restrict__ b_map, const float* __restrict__ cls,
                         float* __restrict__ tokens, float* __restrict__ part1,
                         float* __restrict__ partq1, float* __restrict__ sum2,
                         float* __restrict__ sumsq2) {
    int b = blockIdx.y;
    int bx = blockIdx.x;
    int idx = bx * 256 + threadIdx.x;   // [0, SD)
    int tid = threadIdx.x;
    __shared__ float recip[64];
    __shared__ float sh[512];
    if (tid < 64) {
        int j = tid;
        float div;
        if ((j & 1) == 0)
            div = powf(10000.0f, (float)j * (1.0f / 64.0f));
        else  // reference: 10000^(j-1)/64; overflow->inf -> recip 0 -> arg 0 -> cos=1 (matches f64)
            div = powf(10000.0f, (float)(j - 1)) * (1.0f / 64.0f);
        recip[j] = 1.0f / div;
    }
    __syncthreads();
    float lv = 0.f, lvv = 0.f;
    if (idx < SD) {
        int s = idx >> 6, j = idx & 63;
        float arg = (float)s * recip[j];
        float pv = (j & 1) ? __cosf(arg) : __sinf(arg);
        float v;
        if (s == 0) {
            v = cls[j];
        } else {
            const float* p = images + (size_t)b * (NPATCH * IN_D) + (size_t)(s - 1) * IN_D;
            float acc = b_map[j];
#pragma unroll
            for (int i = 0; i < IN_D; ++i) acc += p[i] * w_map[i * DD + j];
            v = acc;
        }
        v += pv;
        tokens[(size_t)b * SD + idx] = v;
        lv = v; lvv = v * v;
    }
    sh[tid] = lv; sh[256 + tid] = lvv;
    __syncthreads();
    for (int off = 128; off > 0; off >>= 1) {
        if (tid < off) { sh[tid] += sh[tid + off]; sh[256 + tid] += sh[256 + tid + off]; }
        __syncthreads();
    }
    if (tid == 0) {
        part1[b * NTB + bx] = sh[0];
        partq1[b * NTB + bx] = sh[256];
    }
    if (bx == 0) {          // zero the ln2 stat accumulators (k_attn adds later; stream-ordered)
        if (tid == 0) sum2[b] = 0.f;
        if (tid == 1) sumsq2[b] = 0.f;
    }
}

// ---------------- ln1 -> q,k,v in bf16, layout [bh][SP][8]; scale*log2e folded into q ----------------
// Last block per batch additionally zeroes kb pad rows [SS, SP) — required because
// k_attn reads K directly from global (garbage pad -> exp -> inf*0 = NaN would poison PV).
__global__ void k_qkv(const float* __restrict__ tokens, const float* __restrict__ part1,
                      const float* __restrict__ partq1, const float* __restrict__ g1,
                      const float* __restrict__ be1,
                      const float* __restrict__ wq, const float* __restrict__ bq,
                      const float* __restrict__ wk, const float* __restrict__ bk,
                      const float* __restrict__ wv, const float* __restrict__ bv,
                      short* __restrict__ qb, short* __restrict__ kb, short* __restrict__ vb) {
    int b = blockIdx.y, bx = blockIdx.x, tid = threadIdx.x;
    __shared__ float sh[512];
    __shared__ float xs[4][DD];
    __shared__ float stats[2];
    {
        float s = 0.f, ss = 0.f;
        for (int i = tid; i < NTB; i += 256) { s += part1[b * NTB + i]; ss += partq1[b * NTB + i]; }
        sh[tid] = s; sh[256 + tid] = ss;
        __syncthreads();
        for (int off = 128; off > 0; off >>= 1) {
            if (tid < off) { sh[tid] += sh[tid + off]; sh[256 + tid] += sh[256 + tid + off]; }
            __syncthreads();
        }
        if (tid == 0) {
            float mu = sh[0] / (float)SD;
            float var = sh[256] / (float)SD - mu * mu;
            stats[0] = mu;
            stats[1] = rsqrtf(var + EPSF);
        }
        __syncthreads();
    }
    int r = tid >> 6, d = tid & 63;
    int srow = bx * 4 + r;
    if (srow < SS) {
        float t = tokens[((size_t)b * SS + srow) * DD + d];
        xs[r][d] = (t - stats[0]) * stats[1] * g1[srow * DD + d] + be1[srow * DD + d];
    }
    __syncthreads();
    for (int o = tid; o < 768; o += 256) {
        int rr = o / 192;
        int rem = o % 192;
        int which = rem / 64;       // 0=q 1=k 2=v
        int he = rem % 64;
        int h = he >> 3, e = he & 7;
        int s2 = bx * 4 + rr;
        if (s2 >= SS) continue;
        const float* w = (which == 0) ? wq : (which == 1) ? wk : wv;
        const float* bias = (which == 0) ? bq : (which == 1) ? bk : bv;
        float acc = bias[he];
#pragma unroll
        for (int dd = 0; dd < 8; ++dd)
            acc += xs[rr][h * 8 + dd] * w[(h * 8 + dd) * 8 + e];
        if (which == 0) acc *= SCALE_LOG2E;
        short* dst = (which == 0) ? qb : (which == 1) ? kb : vb;
        dst[((size_t)(b * HH + h) * SP + s2) * 8 + e] = f2bf(acc);
    }
    if (bx == NTB - 1) {
        // zero K pad rows [SS, SP) for all heads of this batch: (SP-SS)*HH*8 = 15872 shorts
        for (int i = tid; i < (SP - SS) * HH * 8; i += 256) {
            int rr = i / (HH * 8);          // pad row index 0..30
            int he = i % (HH * 8);
            int hh = he >> 3, e = he & 7;
            kb[((size_t)(b * HH + hh) * SP + SS + rr) * 8 + e] = 0;
        }
    }
}

// ---------------- MFMA flash attention; CLS-row output + ln2-stat accumulation ----------------
// grid (3, HH, BB), 512 thr (8 waves); launch_bounds(512,6) — VGPR budget ~85, NO spill
// (R10 lesson: (512,8) forced VGPR 32 -> 26.7 MB scratch spill -> +12 µs).
// K read directly from global (L2) with 1-deep register prefetch (alias-free).
// P path: double-buffered pipeline (R10 correctness-proven): read P(ch)/V(ch) from parity
// buffer ch&1, compute+write S(ch+1) into parity (ch+1)&1 (disjoint lines, no WAR),
// PV-MFMA consumes after its operands return. Same-address write->read across iters
// is the R3/R5-proven DS in-order guarantee.
__global__ __launch_bounds__(512, 6)
void k_attn(const short* __restrict__ qb, const short* __restrict__ kb, const short* __restrict__ vb,
            const float* __restrict__ tokens, float* __restrict__ out0,
            float* __restrict__ sum2, float* __restrict__ sumsq2) {
    __shared__ __align__(16) short VTs[9 * VTROW];       // 19152 B: V^T rows [e][t]; row 8 = ones(t<SS)
    __shared__ __align__(16) short Ps[8 * 2 * 16 * PSTR];// 20480 B: per-wave double-buffered P [q][t]
    int h = blockIdx.y, b = blockIdx.z;
    int bh = b * HH + h;
    int tid = threadIdx.x;
    int wave = tid >> 6, lane = tid & 63;
    int col = lane & 15, quad = lane >> 4;

    bf16x8 z8 = {0, 0, 0, 0, 0, 0, 0, 0};
    {   // transpose V into VT; row 8 = softmax-denominator ones row (0 in pad: excludes pad P=1 terms)
        const bf16x8* vg = (const bf16x8*)(vb + (size_t)bh * SP * 8);
        for (int t = tid; t < SP; t += 512) {
            if (t < SS) {
                bf16x8 row = vg[t];
#pragma unroll
                for (int e = 0; e < 8; ++e) VTs[e * VTROW + t] = row[e];
                VTs[8 * VTROW + t] = (short)0x3F80;   // bf16 1.0
            } else {
#pragma unroll
                for (int e = 0; e < 9; ++e) VTs[e * VTROW + t] = 0;
            }
        }
    }
    __syncthreads();

    // K B-frag straight from global: quad0 lanes walk rows t0+col / t0+col+16;
    // quads 1-3 read the zeroed pad row (same address across lanes -> broadcast).
    const short* kg = kb + (size_t)bh * SP * 8;
    const short* kp0 = kg + ((quad == 0) ? col * 8 : ZROW * 8);
    const int kstep = (quad == 0) ? 256 : 0;     // shorts per 32-t chunk
    const int koff16 = (quad == 0) ? 128 : 0;
    // V B-frag: lane n=col -> VT row e; cols 9-15 read the ones row (their O columns
    // are computed but never read in the epilogue — harmless finite values)
    const short* vbase_l = VTs + (col < 9 ? col : 8) * VTROW + quad * 8;
    short* pbase = Ps + wave * (2 * 16 * PSTR);
    short* pwr = pbase + (quad * 4) * PSTR + col;        // S-write base (+parity, +r*PSTR)
    const short* prd = pbase + col * PSTR + quad * 8;    // P-read base (+parity)

    float lsum = 0.f, lssq = 0.f;
    int slot = blockIdx.x * 8 + wave;   // 0..23

    for (int qt = slot; qt < NQT; qt += 24) {
        bf16x8 qfrag = z8;
        if (quad == 0) qfrag = *(const bf16x8*)(qb + ((size_t)bh * SP + qt * 16 + col) * 8);
        f32x4 o = {0.f, 0.f, 0.f, 0.f};
        const f32x4 zz = {0.f, 0.f, 0.f, 0.f};
        const short* kptr = kp0;
        // K register prefetch for chunk 0, and emit S(0) into parity buffer 0
        bf16x8 ka = *(const bf16x8*)kptr;
        bf16x8 kb_ = *(const bf16x8*)(kptr + koff16);
        {
            f32x4 s0 = __builtin_amdgcn_mfma_f32_16x16x32_bf16(qfrag, ka, zz, 0, 0, 0);
            f32x4 s1 = __builtin_amdgcn_mfma_f32_16x16x32_bf16(qfrag, kb_, zz, 0, 0, 0);
#pragma unroll
            for (int r = 0; r < 4; ++r) {
                pwr[r * PSTR]      = f2bf_fast(exp2_fast(s0[r]));
                pwr[r * PSTR + 16] = f2bf_fast(exp2_fast(s1[r]));
            }
        }
        for (int ch = 0; ch < NCH; ++ch) {
            // issue P(ch) + V(ch) reads from parity ch&1 (latency overlaps S(ch+1) below)
            bf16x8 pf = *(const bf16x8*)(prd + (ch & 1) * (16 * PSTR));
            bf16x8 vf = *(const bf16x8*)(vbase_l + ch * 32);
            if (ch + 1 < NCH) {
                // prefetch K(ch+1) (registers — alias-free) and emit S(ch+1) into parity (ch+1)&1
                kptr += kstep;
                ka = *(const bf16x8*)kptr;
                kb_ = *(const bf16x8*)(kptr + koff16);
                f32x4 s0 = __builtin_amdgcn_mfma_f32_16x16x32_bf16(qfrag, ka, zz, 0, 0, 0);
                f32x4 s1 = __builtin_amdgcn_mfma_f32_16x16x32_bf16(qfrag, kb_, zz, 0, 0, 0);
                short* pw = pwr + ((ch + 1) & 1) * (16 * PSTR);
#pragma unroll
                for (int r = 0; r < 4; ++r) {
                    pw[r * PSTR]      = f2bf_fast(exp2_fast(s0[r]));
                    pw[r * PSTR + 16] = f2bf_fast(exp2_fast(s1[r]));
                }
            }
            o = __builtin_amdgcn_mfma_f32_16x16x32_bf16(pf, vf, o, 0, 0, 0);
        }
        // epilogue: spill O via per-wave scratch (col 8 = softmax denom l)
        float* Pf = (float*)pbase;
#pragma unroll
        for (int r = 0; r < 4; ++r) Pf[(quad * 4 + r) * 16 + col] = o[r];
#pragma unroll
        for (int pass = 0; pass < 2; ++pass) {
            int idx = lane + pass * 64;    // 16q x 8e
            int qq = idx >> 3, e = idx & 7;
            int qg = qt * 16 + qq;
            if (qg < SS) {
                float num = Pf[qq * 16 + e];
                float l = Pf[qq * 16 + 8];
                float ov = tokens[((size_t)b * SS + qg) * DD + h * 8 + e] + num / l;
                lsum += ov; lssq += ov * ov;
                if (qg == 0) out0[b * DD + h * 8 + e] = ov;
            }
        }
    }

    __syncthreads();
    float* red = (float*)Ps;    // P scratch dead; reuse (needs 4 KB of 20 KB)
    red[tid] = lsum; red[512 + tid] = lssq;
    __syncthreads();
    for (int off = 256; off > 0; off >>= 1) {
        if (tid < off) { red[tid] += red[tid + off]; red[512 + tid] += red[512 + tid + off]; }
        __syncthreads();
    }
    if (tid == 0) {
        atomicAdd(&sum2[b], red[0]);
        atomicAdd(&sumsq2[b], red[512]);
    }
}

// ---------------- final: ln2(row0) -> MLP(+relu) -> residual -> head -> softmax ----------------
__global__ void k_final(const float* __restrict__ out0, const float* __restrict__ sum2,
                        const float* __restrict__ sumsq2, const float* __restrict__ g2,
                        const float* __restrict__ be2, const float* __restrict__ w_enc,
                        const float* __restrict__ b_enc, const float* __restrict__ w_out,
                        const float* __restrict__ b_out, float* __restrict__ out) {
    int b = blockIdx.x;
    int tid = threadIdx.x;  // 64
    __shared__ float xn[DD], hsh[DD], logit[OUTD];
    float n = (float)SD;
    float mu = sum2[b] / n;
    float var = sumsq2[b] / n - mu * mu;
    float rs = rsqrtf(var + EPSF);
    float o = out0[b * DD + tid];
    xn[tid] = (o - mu) * rs * g2[tid] + be2[tid];
    __syncthreads();
    float acc = b_enc[tid];
#pragma unroll
    for (int d = 0; d < DD; ++d) acc += xn[d] * w_enc[d * DD + tid];
    hsh[tid] = o + fmaxf(acc, 0.f);
    __syncthreads();
    if (tid < OUTD) {
        float a = b_out[tid];
#pragma unroll
        for (int d = 0; d < DD; ++d) a += hsh[d] * w_out[d * OUTD + tid];
        logit[tid] = a;
    }
    __syncthreads();
    if (tid == 0) {
        float m = logit[0];
        for (int i = 1; i < OUTD; ++i) m = fmaxf(m, logit[i]);
        float p[OUTD]; float ssum = 0.f;
        for (int i = 0; i < OUTD; ++i) { p[i] = expf(logit[i] - m); ssum += p[i]; }
        for (int i = 0; i < OUTD; ++i) out[b * OUTD + i] = p[i] / ssum;
    }
}

extern "C" void kernel_launch(void* const* d_in, const int* in_sizes, int n_in,
                              void* d_out, int out_size, void* d_ws, size_t ws_size,
                              hipStream_t stream) {
    const float* images = (const float*)d_in[0];
    const float* w_map  = (const float*)d_in[1];
    const float* b_map  = (const float*)d_in[2];
    const float* cls    = (const float*)d_in[3];
    const float* g1     = (const float*)d_in[4];
    const float* be1    = (const float*)d_in[5];
    const float* wq     = (const float*)d_in[6];
    const float* bq     = (const float*)d_in[7];
    const float* wk     = (const float*)d_in[8];
    const float* bk     = (const float*)d_in[9];
    const float* wv     = (const float*)d_in[10];
    const float* bv     = (const float*)d_in[11];
    const float* g2     = (const float*)d_in[12];
    const float* be2    = (const float*)d_in[13];
    const float* w_enc  = (const float*)d_in[14];
    const float* b_enc  = (const float*)d_in[15];
    const float* w_out  = (const float*)d_in[16];
    const float* b_out  = (const float*)d_in[17];
    float* out = (float*)d_out;

    float* ws = (float*)d_ws;
    size_t off = 0;
    float* tokens = ws + off; off += (size_t)BB * SD;
    float* out0   = ws + off; off += BB * DD;
    float* part1  = ws + off; off += BB * NTB;
    float* partq1 = ws + off; off += BB * NTB;
    float* sum2   = ws + off; off += BB;
    float* sumsq2 = ws + off; off += BB;
    short* qb = (short*)(ws + off); off += (size_t)BB * HH * SP * 8 / 2;
    short* kb = (short*)(ws + off); off += (size_t)BB * HH * SP * 8 / 2;
    short* vb = (short*)(ws + off); off += (size_t)BB * HH * SP * 8 / 2;

    k_tokens<<<dim3(NTB, BB), 256, 0, stream>>>(images, w_map, b_map, cls, tokens,
                                                part1, partq1, sum2, sumsq2);
    k_qkv<<<dim3(NTB, BB), 256, 0, stream>>>(tokens, part1, partq1, g1, be1,
                                             wq, bq, wk, bk, wv, bv, qb, kb, vb);
    k_attn<<<dim3(3, HH, BB), 512, 0, stream>>>(qb, kb, vb, tokens, out0, sum2, sumsq2);
    k_final<<<BB, DD, 0, stream>>>(out0, sum2, sumsq2, g2, be2, w_enc, b_enc, w_out, b_out, out);
}

// Round 12
// 181.155 us; speedup vs baseline: 1.0753x; 1.0318x over previous
//
#include <hip/hip_runtime.h>
#include <math.h>

#define BB 32
#define SS 1025
#define DD 64
#define HH 8
#define IN_D 8
#define NPATCH 1024
#define OUTD 9
#define EPSF 1e-5f
#define SD (SS*DD)        // 65600
#define SP 1056           // padded seq = 33*32
#define NQT 65            // ceil(1025/16) q-tiles
#define NCH 33            // 1056/32 t-chunks
#define VTROW 1064        // VT LDS row stride (shorts)
#define PSTR 40           // P row stride in shorts ([q][k], 32 k + 8 pad); 80B keeps b128 reads aligned
#define NTB 257           // blocks per batch for token/stat kernels
#define ZROW 1055         // guaranteed-zero K row (pad, zeroed by k_qkv)

typedef __attribute__((ext_vector_type(8))) short bf16x8;
typedef __attribute__((ext_vector_type(4))) float f32x4;

// fold softmax scale 1/sqrt(8) and exp->exp2 into Q
#define SCALE_LOG2E (0.35355339059327378f * 1.4426950408889634f)

#if __has_builtin(__builtin_amdgcn_exp2f)
__device__ __forceinline__ float exp2_fast(float x) { return __builtin_amdgcn_exp2f(x); }
#else
__device__ __forceinline__ float exp2_fast(float x) {
    float r; asm("v_exp_f32 %0, %1" : "=v"(r) : "v"(x)); return r;
}
#endif

__device__ __forceinline__ short f2bf(float f) {
    union { float f; unsigned u; } a; a.f = f;
    unsigned r = a.u + 0x7FFFu + ((a.u >> 16) & 1u);  // RNE
    return (short)(r >> 16);
}
// pack two floats to bf16 pair (round-nearest-ties-away, same bits as f2bf_fast):
// low short = bf16(lo), high short = bf16(hi).
// v_perm_b32: dst bytes 0-3 select from src1, 4-7 from src0; sel 0x07060302 ->
// [src1.hi16 | src0.hi16] with src1 in the LOW half.
__device__ __forceinline__ unsigned pack_bf16x2(float lo, float hi) {
    unsigned ul = __float_as_uint(lo) + 0x8000u;
    unsigned uh = __float_as_uint(hi) + 0x8000u;
    return __builtin_amdgcn_perm(uh, ul, 0x07060302u);
}

// k-permutation shared by P-store and V-store: sigma(k) = t-offset within 32-t chunk.
// sigma(2c+tile) = c + 16*tile  (c=0..15)  <=>  sigma(k) = 16*(k&1) + 4*(k>>3) + ((k>>1)&3)
__device__ __forceinline__ int sigma32(int k) {
    return 16 * (k & 1) + 4 * (k >> 3) + ((k >> 1) & 3);
}

// ---------------- tokens = [cls; patches@w_map+b_map] + pos; per-block partial ln1 stats ----------------
__global__ void k_tokens(const float* __restrict__ images, const float* __restrict__ w_map,
                         const float* __restrict__ b_map, const float* __restrict__ cls,
                         float* __restrict__ tokens, float* __restrict__ part1,
                         float* __restrict__ partq1, float* __restrict__ sum2,
                         float* __restrict__ sumsq2) {
    int b = blockIdx.y;
    int bx = blockIdx.x;
    int idx = bx * 256 + threadIdx.x;   // [0, SD)
    int tid = threadIdx.x;
    __shared__ float recip[64];
    __shared__ float sh[512];
    if (tid < 64) {
        int j = tid;
        float div;
        if ((j & 1) == 0)
            div = powf(10000.0f, (float)j * (1.0f / 64.0f));
        else  // reference: 10000^(j-1)/64; overflow->inf -> recip 0 -> arg 0 -> cos=1 (matches f64)
            div = powf(10000.0f, (float)(j - 1)) * (1.0f / 64.0f);
        recip[j] = 1.0f / div;
    }
    __syncthreads();
    float lv = 0.f, lvv = 0.f;
    if (idx < SD) {
        int s = idx >> 6, j = idx & 63;
        float arg = (float)s * recip[j];
        float pv = (j & 1) ? __cosf(arg) : __sinf(arg);
        float v;
        if (s == 0) {
            v = cls[j];
        } else {
            const float* p = images + (size_t)b * (NPATCH * IN_D) + (size_t)(s - 1) * IN_D;
            float acc = b_map[j];
#pragma unroll
            for (int i = 0; i < IN_D; ++i) acc += p[i] * w_map[i * DD + j];
            v = acc;
        }
        v += pv;
        tokens[(size_t)b * SD + idx] = v;
        lv = v; lvv = v * v;
    }
    sh[tid] = lv; sh[256 + tid] = lvv;
    __syncthreads();
    for (int off = 128; off > 0; off >>= 1) {
        if (tid < off) { sh[tid] += sh[tid + off]; sh[256 + tid] += sh[256 + tid + off]; }
        __syncthreads();
    }
    if (tid == 0) {
        part1[b * NTB + bx] = sh[0];
        partq1[b * NTB + bx] = sh[256];
    }
    if (bx == 0) {          // zero the ln2 stat accumulators (k_attn adds later; stream-ordered)
        if (tid == 0) sum2[b] = 0.f;
        if (tid == 1) sumsq2[b] = 0.f;
    }
}

// ---------------- ln1 -> q,k,v in bf16, layout [bh][SP][8]; scale*log2e folded into q ----------------
// Last block per batch additionally zeroes kb pad rows [SS, SP) — required because
// k_attn reads K directly from global (garbage pad -> exp -> inf*0 = NaN would poison PV).
__global__ void k_qkv(const float* __restrict__ tokens, const float* __restrict__ part1,
                      const float* __restrict__ partq1, const float* __restrict__ g1,
                      const float* __restrict__ be1,
                      const float* __restrict__ wq, const float* __restrict__ bq,
                      const float* __restrict__ wk, const float* __restrict__ bk,
                      const float* __restrict__ wv, const float* __restrict__ bv,
                      short* __restrict__ qb, short* __restrict__ kb, short* __restrict__ vb) {
    int b = blockIdx.y, bx = blockIdx.x, tid = threadIdx.x;
    __shared__ float sh[512];
    __shared__ float xs[4][DD];
    __shared__ float stats[2];
    {
        float s = 0.f, ss = 0.f;
        for (int i = tid; i < NTB; i += 256) { s += part1[b * NTB + i]; ss += partq1[b * NTB + i]; }
        sh[tid] = s; sh[256 + tid] = ss;
        __syncthreads();
        for (int off = 128; off > 0; off >>= 1) {
            if (tid < off) { sh[tid] += sh[tid + off]; sh[256 + tid] += sh[256 + tid + off]; }
            __syncthreads();
        }
        if (tid == 0) {
            float mu = sh[0] / (float)SD;
            float var = sh[256] / (float)SD - mu * mu;
            stats[0] = mu;
            stats[1] = rsqrtf(var + EPSF);
        }
        __syncthreads();
    }
    int r = tid >> 6, d = tid & 63;
    int srow = bx * 4 + r;
    if (srow < SS) {
        float t = tokens[((size_t)b * SS + srow) * DD + d];
        xs[r][d] = (t - stats[0]) * stats[1] * g1[srow * DD + d] + be1[srow * DD + d];
    }
    __syncthreads();
    for (int o = tid; o < 768; o += 256) {
        int rr = o / 192;
        int rem = o % 192;
        int which = rem / 64;       // 0=q 1=k 2=v
        int he = rem % 64;
        int h = he >> 3, e = he & 7;
        int s2 = bx * 4 + rr;
        if (s2 >= SS) continue;
        const float* w = (which == 0) ? wq : (which == 1) ? wk : wv;
        const float* bias = (which == 0) ? bq : (which == 1) ? bk : bv;
        float acc = bias[he];
#pragma unroll
        for (int dd = 0; dd < 8; ++dd)
            acc += xs[rr][h * 8 + dd] * w[(h * 8 + dd) * 8 + e];
        if (which == 0) acc *= SCALE_LOG2E;
        short* dst = (which == 0) ? qb : (which == 1) ? kb : vb;
        dst[((size_t)(b * HH + h) * SP + s2) * 8 + e] = f2bf(acc);
    }
    if (bx == NTB - 1) {
        // zero K pad rows [SS, SP) for all heads of this batch: (SP-SS)*HH*8 = 15872 shorts
        for (int i = tid; i < (SP - SS) * HH * 8; i += 256) {
            int rr = i / (HH * 8);          // pad row index 0..30
            int he = i % (HH * 8);
            int hh = he >> 3, e = he & 7;
            kb[((size_t)(b * HH + hh) * SP + SS + rr) * 8 + e] = 0;
        }
    }
}

// ---------------- MFMA flash attention; CLS-row output + ln2-stat accumulation ----------------
// grid (3, HH, BB), 512 thr (8 waves); launch_bounds(512,6) — no VGPR spill (R10 lesson).
// K read directly from global (L2); quads 1-3 broadcast the zeroed pad row ZROW.
// DS-op diet (R11 lesson: LDS pipe is the binding resource, ~10 ops/chunk = ~45 µs):
//   P stored k-PERMUTED: P_store[q][2c+tile] so each lane writes its (s0[r], s1[r]) pair
//   as ONE dword -> 4x ds_write_b32 (2-way banks, free) instead of 8x ds_write_b16.
//   V is staged into VT with the SAME k-permutation sigma32, so both PV operands remain
//   single ds_read_b128 (MFMA k-order is arbitrary if A and B agree). 6 DS ops/chunk.
// P parity double-buffer retained (R10-proven correctness; disjoint lines, no WAR).
__global__ __launch_bounds__(512, 6)
void k_attn(const short* __restrict__ qb, const short* __restrict__ kb, const short* __restrict__ vb,
            const float* __restrict__ tokens, float* __restrict__ out0,
            float* __restrict__ sum2, float* __restrict__ sumsq2) {
    __shared__ __align__(16) short VTs[9 * VTROW];       // 19152 B: V^T rows [e][perm-idx]; row 8 = ones(t<SS)
    __shared__ __align__(16) short Ps[8 * 2 * 16 * PSTR];// 20480 B: per-wave double-buffered P [q][k]
    int h = blockIdx.y, b = blockIdx.z;
    int bh = b * HH + h;
    int tid = threadIdx.x;
    int wave = tid >> 6, lane = tid & 63;
    int col = lane & 15, quad = lane >> 4;

    bf16x8 z8 = {0, 0, 0, 0, 0, 0, 0, 0};
    {   // stage V^T k-permuted: VTs[e][32*ch + k] = V[t][e] with t = 32*ch + sigma32(k).
        // row 8 = softmax-denominator ones (0 where t >= SS: excludes pad P=1 terms).
        const bf16x8* vg = (const bf16x8*)(vb + (size_t)bh * SP * 8);
        for (int i = tid; i < SP; i += 512) {
            int t = (i & ~31) | sigma32(i & 31);
            if (t < SS) {
                bf16x8 row = vg[t];
#pragma unroll
                for (int e = 0; e < 8; ++e) VTs[e * VTROW + i] = row[e];
                VTs[8 * VTROW + i] = (short)0x3F80;   // bf16 1.0
            } else {
#pragma unroll
                for (int e = 0; e < 9; ++e) VTs[e * VTROW + i] = 0;
            }
        }
    }
    __syncthreads();

    // K B-frag straight from global: quad0 lanes walk rows t0+col / t0+col+16;
    // quads 1-3 read the zeroed pad row (same address across lanes -> broadcast).
    const short* kg = kb + (size_t)bh * SP * 8;
    const short* kp0 = kg + ((quad == 0) ? col * 8 : ZROW * 8);
    const int kstep = (quad == 0) ? 256 : 0;     // shorts per 32-t chunk
    const int koff16 = (quad == 0) ? 128 : 0;
    // V B-frag: lane n=col -> VT row e; cols 9-15 read the ones row (their O columns
    // are computed but never read in the epilogue — harmless finite values)
    const short* vbase_l = VTs + (col < 9 ? col : 8) * VTROW + quad * 8;
    short* pbase = Ps + wave * (2 * 16 * PSTR);
    short* pwr = pbase + (quad * 4) * PSTR + 2 * col;    // S-write base (+parity, +r*PSTR); dword-aligned
    const short* prd = pbase + col * PSTR + quad * 8;    // P-read base (+parity)

    float lsum = 0.f, lssq = 0.f;
    int slot = blockIdx.x * 8 + wave;   // 0..23

    for (int qt = slot; qt < NQT; qt += 24) {
        bf16x8 qfrag = z8;
        if (quad == 0) qfrag = *(const bf16x8*)(qb + ((size_t)bh * SP + qt * 16 + col) * 8);
        f32x4 o = {0.f, 0.f, 0.f, 0.f};
        const f32x4 zz = {0.f, 0.f, 0.f, 0.f};
        const short* kptr = kp0;
        // K register prefetch for chunk 0, and emit S(0) into parity buffer 0
        bf16x8 ka = *(const bf16x8*)kptr;
        bf16x8 kb_ = *(const bf16x8*)(kptr + koff16);
        {
            f32x4 s0 = __builtin_amdgcn_mfma_f32_16x16x32_bf16(qfrag, ka, zz, 0, 0, 0);
            f32x4 s1 = __builtin_amdgcn_mfma_f32_16x16x32_bf16(qfrag, kb_, zz, 0, 0, 0);
#pragma unroll
            for (int r = 0; r < 4; ++r)
                *(unsigned*)(pwr + r * PSTR) = pack_bf16x2(exp2_fast(s0[r]), exp2_fast(s1[r]));
        }
        for (int ch = 0; ch < NCH; ++ch) {
            // issue P(ch) + V(ch) reads from parity ch&1
            bf16x8 pf = *(const bf16x8*)(prd + (ch & 1) * (16 * PSTR));
            bf16x8 vf = *(const bf16x8*)(vbase_l + ch * 32);
            if (ch + 1 < NCH) {
                // prefetch K(ch+1) (registers — alias-free) and emit S(ch+1) into parity (ch+1)&1
                kptr += kstep;
                ka = *(const bf16x8*)kptr;
                kb_ = *(const bf16x8*)(kptr + koff16);
                f32x4 s0 = __builtin_amdgcn_mfma_f32_16x16x32_bf16(qfrag, ka, zz, 0, 0, 0);
                f32x4 s1 = __builtin_amdgcn_mfma_f32_16x16x32_bf16(qfrag, kb_, zz, 0, 0, 0);
                short* pw = pwr + ((ch + 1) & 1) * (16 * PSTR);
#pragma unroll
                for (int r = 0; r < 4; ++r)
                    *(unsigned*)(pw + r * PSTR) = pack_bf16x2(exp2_fast(s0[r]), exp2_fast(s1[r]));
            }
            o = __builtin_amdgcn_mfma_f32_16x16x32_bf16(pf, vf, o, 0, 0, 0);
        }
        // epilogue: spill O via per-wave scratch (col 8 = softmax denom l)
        float* Pf = (float*)pbase;
#pragma unroll
        for (int r = 0; r < 4; ++r) Pf[(quad * 4 + r) * 16 + col] = o[r];
#pragma unroll
        for (int pass = 0; pass < 2; ++pass) {
            int idx = lane + pass * 64;    // 16q x 8e
            int qq = idx >> 3, e = idx & 7;
            int qg = qt * 16 + qq;
            if (qg < SS) {
                float num = Pf[qq * 16 + e];
                float l = Pf[qq * 16 + 8];
                float ov = tokens[((size_t)b * SS + qg) * DD + h * 8 + e] + num / l;
                lsum += ov; lssq += ov * ov;
                if (qg == 0) out0[b * DD + h * 8 + e] = ov;
            }
        }
    }

    __syncthreads();
    float* red = (float*)Ps;    // P scratch dead; reuse (needs 4 KB of 20 KB)
    red[tid] = lsum; red[512 + tid] = lssq;
    __syncthreads();
    for (int off = 256; off > 0; off >>= 1) {
        if (tid < off) { red[tid] += red[tid + off]; red[512 + tid] += red[512 + tid + off]; }
        __syncthreads();
    }
    if (tid == 0) {
        atomicAdd(&sum2[b], red[0]);
        atomicAdd(&sumsq2[b], red[512]);
    }
}

// ---------------- final: ln2(row0) -> MLP(+relu) -> residual -> head -> softmax ----------------
__global__ void k_final(const float* __restrict__ out0, const float* __restrict__ sum2,
                        const float* __restrict__ sumsq2, const float* __restrict__ g2,
                        const float* __restrict__ be2, const float* __restrict__ w_enc,
                        const float* __restrict__ b_enc, const float* __restrict__ w_out,
                        const float* __restrict__ b_out, float* __restrict__ out) {
    int b = blockIdx.x;
    int tid = threadIdx.x;  // 64
    __shared__ float xn[DD], hsh[DD], logit[OUTD];
    float n = (float)SD;
    float mu = sum2[b] / n;
    float var = sumsq2[b] / n - mu * mu;
    float rs = rsqrtf(var + EPSF);
    float o = out0[b * DD + tid];
    xn[tid] = (o - mu) * rs * g2[tid] + be2[tid];
    __syncthreads();
    float acc = b_enc[tid];
#pragma unroll
    for (int d = 0; d < DD; ++d) acc += xn[d] * w_enc[d * DD + tid];
    hsh[tid] = o + fmaxf(acc, 0.f);
    __syncthreads();
    if (tid < OUTD) {
        float a = b_out[tid];
#pragma unroll
        for (int d = 0; d < DD; ++d) a += hsh[d] * w_out[d * OUTD + tid];
        logit[tid] = a;
    }
    __syncthreads();
    if (tid == 0) {
        float m = logit[0];
        for (int i = 1; i < OUTD; ++i) m = fmaxf(m, logit[i]);
        float p[OUTD]; float ssum = 0.f;
        for (int i = 0; i < OUTD; ++i) { p[i] = expf(logit[i] - m); ssum += p[i]; }
        for (int i = 0; i < OUTD; ++i) out[b * OUTD + i] = p[i] / ssum;
    }
}

extern "C" void kernel_launch(void* const* d_in, const int* in_sizes, int n_in,
                              void* d_out, int out_size, void* d_ws, size_t ws_size,
                              hipStream_t stream) {
    const float* images = (const float*)d_in[0];
    const float* w_map  = (const float*)d_in[1];
    const float* b_map  = (const float*)d_in[2];
    const float* cls    = (const float*)d_in[3];
    const float* g1     = (const float*)d_in[4];
    const float* be1    = (const float*)d_in[5];
    const float* wq     = (const float*)d_in[6];
    const float* bq     = (const float*)d_in[7];
    const float* wk     = (const float*)d_in[8];
    const float* bk     = (const float*)d_in[9];
    const float* wv     = (const float*)d_in[10];
    const float* bv     = (const float*)d_in[11];
    const float* g2     = (const float*)d_in[12];
    const float* be2    = (const float*)d_in[13];
    const float* w_enc  = (const float*)d_in[14];
    const float* b_enc  = (const float*)d_in[15];
    const float* w_out  = (const float*)d_in[16];
    const float* b_out  = (const float*)d_in[17];
    float* out = (float*)d_out;

    float* ws = (float*)d_ws;
    size_t off = 0;
    float* tokens = ws + off; off += (size_t)BB * SD;
    float* out0   = ws + off; off += BB * DD;
    float* part1  = ws + off; off += BB * NTB;
    float* partq1 = ws + off; off += BB * NTB;
    float* sum2   = ws + off; off += BB;
    float* sumsq2 = ws + off; off += BB;
    short* qb = (short*)(ws + off); off += (size_t)BB * HH * SP * 8 / 2;
    short* kb = (short*)(ws + off); off += (size_t)BB * HH * SP * 8 / 2;
    short* vb = (short*)(ws + off); off += (size_t)BB * HH * SP * 8 / 2;

    k_tokens<<<dim3(NTB, BB), 256, 0, stream>>>(images, w_map, b_map, cls, tokens,
                                                part1, partq1, sum2, sumsq2);
    k_qkv<<<dim3(NTB, BB), 256, 0, stream>>>(tokens, part1, partq1, g1, be1,
                                             wq, bq, wk, bk, wv, bv, qb, kb, vb);
    k_attn<<<dim3(3, HH, BB), 512, 0, stream>>>(qb, kb, vb, tokens, out0, sum2, sumsq2);
    k_final<<<BB, DD, 0, stream>>>(out0, sum2, sumsq2, g2, be2, w_enc, b_enc, w_out, b_out, out);
}